// Round 12
// baseline (602.474 us; speedup 1.0000x reference)
//
#include <hip/hip_runtime.h>

#define CRF_B 256
#define CRF_L 1024
#define CRF_T 128
#define WS_STRIDE 264   // per batch: xf[128], xb[128], kf, kb, gold, pad

typedef __attribute__((ext_vector_type(8))) short bf16x8;
typedef __attribute__((ext_vector_type(4))) float f32x4;
typedef __attribute__((ext_vector_type(4))) unsigned u32x4;
typedef __attribute__((ext_vector_type(2))) short short2v;

#define MF(a, b, c_) __builtin_amdgcn_mfma_f32_16x16x32_bf16((a), (b), (c_), 0, 0, 0)

static __device__ __forceinline__ unsigned short f2bf(float x) {
    union { float f; unsigned u; } v; v.f = x;
    unsigned r = v.u + 0x7FFFu + ((v.u >> 16) & 1u);   // RNE (one-time E build)
    return (unsigned short)(r >> 16);
}
// truncating bf16 pair pack [b:a]
static __device__ __forceinline__ unsigned pack2(float a, float b) {
    return (__builtin_bit_cast(unsigned, b) & 0xFFFF0000u) |
           (__builtin_bit_cast(unsigned, a) >> 16);
}
static __device__ __forceinline__ short2v bmax2(short2v a, short2v b) {
    return __builtin_elementwise_max(a, b);   // bf16>=0: i16 order-preserving
}
static __device__ __forceinline__ short2v u2s(unsigned w) {
    return __builtin_bit_cast(short2v, w);
}

// One chain-step. No LDS, no barrier: redistribution via 16 ds_bpermute.
// sigma(pos=32kt+8g2+2u+p) = 16*(2kt+p) + (4g2+u); A built by shfl placement,
// B built with same sigma -> cancels (operand symmetry).
// Freeze: chain stops updating past its own nsteps (runs to wave's maxns).
// Stale norm every 2 steps; sig applied exactly when kap += ln (exact pair).
#define STEP_CH(S, X, FC, PF, KAP, SIG, LN, NS, LEN, FBP, DONORM) do {         \
    const bool up_ = (S) <= (NS);                                              \
    (KAP) += up_ ? (LN) : 0.0f;                                                \
    unsigned pk0_, pk1_, pk2_, pk3_;                                           \
    if (isf) {                                                                 \
        pk0_ = pack2(X[0], X[1]); pk1_ = pack2(X[2], X[3]);                    \
        pk2_ = pack2(X[4], X[5]); pk3_ = pack2(X[6], X[7]);                    \
    } else {                                                                   \
        pk0_ = pack2(FC[0]*(SIG)*X[0], FC[1]*(SIG)*X[1]);                      \
        pk1_ = pack2(FC[2]*(SIG)*X[2], FC[3]*(SIG)*X[3]);                      \
        pk2_ = pack2(FC[4]*(SIG)*X[4], FC[5]*(SIG)*X[5]);                      \
        pk3_ = pack2(FC[6]*(SIG)*X[6], FC[7]*(SIG)*X[7]);                      \
    }                                                                          \
    unsigned w00_=__shfl(pk0_,sl0,64), w01_=__shfl(pk0_,sl1,64),               \
             w02_=__shfl(pk0_,sl2,64), w03_=__shfl(pk0_,sl3,64);               \
    unsigned w10_=__shfl(pk1_,sl0,64), w11_=__shfl(pk1_,sl1,64),               \
             w12_=__shfl(pk1_,sl2,64), w13_=__shfl(pk1_,sl3,64);               \
    unsigned w20_=__shfl(pk2_,sl0,64), w21_=__shfl(pk2_,sl1,64),               \
             w22_=__shfl(pk2_,sl2,64), w23_=__shfl(pk2_,sl3,64);               \
    unsigned w30_=__shfl(pk3_,sl0,64), w31_=__shfl(pk3_,sl1,64),               \
             w32_=__shfl(pk3_,sl2,64), w33_=__shfl(pk3_,sl3,64);               \
    u32x4 q0_ = {w00_, w01_, w02_, w03_};                                      \
    u32x4 q1_ = {w10_, w11_, w12_, w13_};                                      \
    u32x4 q2_ = {w20_, w21_, w22_, w23_};                                      \
    u32x4 q3_ = {w30_, w31_, w32_, w33_};                                      \
    bf16x8 A0_ = __builtin_bit_cast(bf16x8, q0_);                              \
    bf16x8 A1_ = __builtin_bit_cast(bf16x8, q1_);                              \
    bf16x8 A2_ = __builtin_bit_cast(bf16x8, q2_);                              \
    bf16x8 A3_ = __builtin_bit_cast(bf16x8, q3_);                              \
    f32x4 ac_[8];                                                              \
    _Pragma("unroll") for (int m_ = 0; m_ < 8; ++m_) ac_[m_] = MF(A0_, Bf[m_][0], Z);        \
    _Pragma("unroll") for (int m_ = 0; m_ < 8; ++m_) ac_[m_] = MF(A1_, Bf[m_][1], ac_[m_]);  \
    _Pragma("unroll") for (int m_ = 0; m_ < 8; ++m_) ac_[m_] = MF(A2_, Bf[m_][2], ac_[m_]);  \
    _Pragma("unroll") for (int m_ = 0; m_ < 8; ++m_) ac_[m_] = MF(A3_, Bf[m_][3], ac_[m_]);  \
    _Pragma("unroll") for (int m_ = 0; m_ < 8; ++m_) {                         \
        float xn_ = isf ? (FC[m_] * (SIG)) * ac_[m_][0] : ac_[m_][0];          \
        X[m_] = up_ ? xn_ : X[m_];                                             \
    }                                                                          \
    { int r_ = isf ? ((S) + 3) : ((LEN) - (S) - 3);                            \
      r_ = r_ < 0 ? 0 : (r_ > CRF_L - 1 ? CRF_L - 1 : r_);                     \
      const float* rp_ = (FBP) + (size_t)r_ * CRF_T;                           \
      _Pragma("unroll") for (int m_ = 0; m_ < 8; ++m_) {                       \
          FC[m_] = __expf(PF[m_]); PF[m_] = rp_[16 * m_ + c]; } }              \
    if (DONORM) {                                                              \
        short2v t0_ = bmax2(bmax2(u2s(w00_), u2s(w01_)), bmax2(u2s(w02_), u2s(w03_)));  \
        short2v t1_ = bmax2(bmax2(u2s(w10_), u2s(w11_)), bmax2(u2s(w12_), u2s(w13_)));  \
        short2v t2_ = bmax2(bmax2(u2s(w20_), u2s(w21_)), bmax2(u2s(w22_), u2s(w23_)));  \
        short2v t3_ = bmax2(bmax2(u2s(w30_), u2s(w31_)), bmax2(u2s(w32_), u2s(w33_)));  \
        short2v tm_ = bmax2(bmax2(t0_, t1_), bmax2(t2_, t3_));                 \
        unsigned mu_ = __builtin_bit_cast(unsigned, tm_);                      \
        float nm_ = fmaxf(__builtin_bit_cast(float, mu_ << 16),                \
                          __builtin_bit_cast(float, mu_ & 0xFFFF0000u));       \
        nm_ = fmaxf(nm_, __shfl_xor(nm_, 16, 64));                             \
        nm_ = fmaxf(nm_, __shfl_xor(nm_, 32, 64));                             \
        (SIG) = __builtin_amdgcn_rcpf(nm_); (LN) = __logf(nm_);                \
    } else { (SIG) = 1.0f; (LN) = 0.0f; }                                      \
} while (0)

// 64 blocks x 256 threads = 256 waves; wave gw handles TWO same-direction
// chains: dir = gw&1, batches bA = gw>>1 and bB = bA+128 (shared B-set).
// Fully wave-autonomous: no barriers, no LDS.
__global__ __launch_bounds__(256, 1) void forward_kernel(
    const float* __restrict__ trans, const float* __restrict__ feats,
    const int* __restrict__ mask, const int* __restrict__ tags,
    float* __restrict__ ws)
{
    const int t    = threadIdx.x;
    const int gw   = blockIdx.x * 4 + (t >> 6);   // 0..255
    const int dir  = gw & 1;
    const bool isf = (dir == 0);
    const int bA   = gw >> 1;                      // 0..127
    const int bB   = bA + 128;
    const int lane = t & 63;
    const int g2   = lane >> 4;
    const int c    = lane & 15;
    const int sl0  = 4 * g2, sl1 = sl0 + 1, sl2 = sl0 + 2, sl3 = sl0 + 3;

    // ---- per-batch length + gold (wave-private, one-time) ----
    int lenA = 0, lenB = 0; float goldA = 0.0f, goldB = 0.0f;
    {
        const int baA = bA * CRF_L, baB = bB * CRF_L;
        for (int l = lane; l < CRF_L; l += 64) {
            int mA = mask[baA + l], mB = mask[baB + l];
            lenA += (mA != 0); lenB += (mB != 0);
            if (isf) {
                if (mA) { int tg = tags[baA + l];
                    float gv = feats[(size_t)(baA + l) * CRF_T + tg];
                    if (l > 0) gv += trans[tags[baA + l - 1] * CRF_T + tg];
                    goldA += gv; }
                if (mB) { int tg = tags[baB + l];
                    float gv = feats[(size_t)(baB + l) * CRF_T + tg];
                    if (l > 0) gv += trans[tags[baB + l - 1] * CRF_T + tg];
                    goldB += gv; }
            }
        }
#pragma unroll
        for (int o = 32; o > 0; o >>= 1) {
            lenA += __shfl_xor(lenA, o, 64); lenB += __shfl_xor(lenB, o, 64);
            goldA += __shfl_xor(goldA, o, 64); goldB += __shfl_xor(goldB, o, 64);
        }
    }

    // ---- B fragments with sigma k-map (one-time; shared by both chains) ----
    bf16x8 Bf[8][4];
#pragma unroll
    for (int m = 0; m < 8; ++m) {
        const int col = 16 * m + c;
#pragma unroll
        for (int kt = 0; kt < 4; ++kt)
#pragma unroll
            for (int e = 0; e < 8; ++e) {
                int tag = 16 * (2 * kt + (e & 1)) + (4 * g2 + (e >> 1));  // sigma
                int idx = isf ? (tag * CRF_T + col) : (col * CRF_T + tag);
                Bf[m][kt][e] = (short)f2bf(__expf(trans[idx]));
            }
    }

    // ---- chain init ----
    const float* fbA = feats + (size_t)bA * CRF_L * CRF_T;
    const float* fbB = feats + (size_t)bB * CRF_L * CRF_T;
    float xA[8], FcA[8], pfA[8], xB[8], FcB[8], pfB[8];
    float kapA = 0.0f, sigA = 1.0f, lnA = 0.0f;
    float kapB = 0.0f, sigB = 1.0f, lnB = 0.0f;
    int nsA, nsB;
    if (isf) {
        nsA = lenA >> 1;  nsB = lenB >> 1;
#pragma unroll
        for (int m = 0; m < 8; ++m) {
            xA[m]  = __expf(fbA[16 * m + c]);
            FcA[m] = __expf(fbA[CRF_T + 16 * m + c]);
            pfA[m] = fbA[2 * CRF_T + 16 * m + c];
            xB[m]  = __expf(fbB[16 * m + c]);
            FcB[m] = __expf(fbB[CRF_T + 16 * m + c]);
            pfB[m] = fbB[2 * CRF_T + 16 * m + c];
        }
    } else {
        nsA = lenA - 1 - (lenA >> 1);  nsB = lenB - 1 - (lenB >> 1);
#pragma unroll
        for (int m = 0; m < 8; ++m) {
            xA[m]  = 1.0f;
            FcA[m] = __expf(fbA[(size_t)(lenA - 1) * CRF_T + 16 * m + c]);
            pfA[m] = fbA[(size_t)(lenA - 2) * CRF_T + 16 * m + c];
            xB[m]  = 1.0f;
            FcB[m] = __expf(fbB[(size_t)(lenB - 1) * CRF_T + 16 * m + c]);
            pfB[m] = fbB[(size_t)(lenB - 2) * CRF_T + 16 * m + c];
        }
    }

    const int maxns = nsA > nsB ? nsA : nsB;
    const f32x4 Z = {};

    int s = 1;
    for (; s + 1 <= maxns; s += 2) {
        STEP_CH(s,     xA, FcA, pfA, kapA, sigA, lnA, nsA, lenA, fbA, true);
        STEP_CH(s,     xB, FcB, pfB, kapB, sigB, lnB, nsB, lenB, fbB, true);
        STEP_CH(s + 1, xA, FcA, pfA, kapA, sigA, lnA, nsA, lenA, fbA, false);
        STEP_CH(s + 1, xB, FcB, pfB, kapB, sigB, lnB, nsB, lenB, fbB, false);
    }
    if (s <= maxns) {
        STEP_CH(s, xA, FcA, pfA, kapA, sigA, lnA, nsA, lenA, fbA, true);
        STEP_CH(s, xB, FcB, pfB, kapB, sigB, lnB, nsB, lenB, fbB, true);
    }

    // ---- write both chains' frozen midpoint states ----
    if (g2 == 0) {
#pragma unroll
        for (int m = 0; m < 8; ++m) {
            ws[(size_t)bA * WS_STRIDE + dir * 128 + 16 * m + c] = xA[m];
            ws[(size_t)bB * WS_STRIDE + dir * 128 + 16 * m + c] = xB[m];
        }
    }
    if (lane == 0) {
        ws[(size_t)bA * WS_STRIDE + 256 + dir] = kapA;
        ws[(size_t)bB * WS_STRIDE + 256 + dir] = kapB;
        if (isf) {
            ws[(size_t)bA * WS_STRIDE + 258] = goldA;
            ws[(size_t)bB * WS_STRIDE + 258] = goldB;
        }
    }
}

// one block, thread t = batch t: loss_b = kf + kb + log(sum xf.xb) - gold
__global__ __launch_bounds__(256) void combine_kernel(
    const float* __restrict__ ws, float* __restrict__ out)
{
    const int t    = threadIdx.x;
    const int lane = t & 63;
    const int w    = t >> 6;
    const float4* pf = (const float4*)(ws + (size_t)t * WS_STRIDE);
    const float4* pb = pf + 32;
    float dot = 0.0f;
#pragma unroll
    for (int k = 0; k < 32; ++k) {
        float4 a = pf[k], bb = pb[k];
        dot += a.x * bb.x + a.y * bb.y + a.z * bb.z + a.w * bb.w;
    }
    const float* ps = ws + (size_t)t * WS_STRIDE;
    float val = ps[256] + ps[257] + __logf(dot) - ps[258];
    for (int o = 32; o > 0; o >>= 1) val += __shfl_down(val, o, 64);
    __shared__ float sw[4];
    if (lane == 0) sw[w] = val;
    __syncthreads();
    if (t == 0) out[0] = sw[0] + sw[1] + sw[2] + sw[3];
}

extern "C" void kernel_launch(void* const* d_in, const int* in_sizes, int n_in,
                              void* d_out, int out_size, void* d_ws, size_t ws_size,
                              hipStream_t stream) {
    const float* trans = (const float*)d_in[0];
    const float* feats = (const float*)d_in[1];
    const int*   mask  = (const int*)d_in[2];
    const int*   tags  = (const int*)d_in[3];
    float*       out   = (float*)d_out;
    float*       ws    = (float*)d_ws;

    hipLaunchKernelGGL(forward_kernel, dim3(64), dim3(256), 0, stream,
                       trans, feats, mask, tags, ws);
    hipLaunchKernelGGL(combine_kernel, dim3(1), dim3(256), 0, stream, ws, out);
}

// Round 13
// 465.448 us; speedup vs baseline: 1.2944x; 1.2944x over previous
//
#include <hip/hip_runtime.h>

#define CRF_B 256
#define CRF_L 1024
#define CRF_T 128
#define WS_STRIDE 264   // per batch: xf[128], xb[128], kf, kb, gold, len, pad

typedef __attribute__((ext_vector_type(8))) short bf16x8;
typedef __attribute__((ext_vector_type(4))) float f32x4;
typedef __attribute__((ext_vector_type(4))) unsigned u32x4;

#define MF(a,b,c_) __builtin_amdgcn_mfma_f32_16x16x32_bf16((a),(b),(c_),0,0,0)

static __device__ __forceinline__ unsigned short f2bf(float x) {
    union { float f; unsigned u; } v; v.f = x;
    unsigned r = v.u + 0x7FFFu + ((v.u >> 16) & 1u);   // RNE (one-time E build)
    return (unsigned short)(r >> 16);
}
// truncating bf16 pair pack [b:a]
static __device__ __forceinline__ unsigned pack2(float a, float b) {
    return (__builtin_bit_cast(unsigned, b) & 0xFFFF0000u) |
           (__builtin_bit_cast(unsigned, a) >> 16);
}

__global__ __launch_bounds__(256) void zero_ws_kernel(float* __restrict__ ws) {
    int b = threadIdx.x;
    ws[(size_t)b*WS_STRIDE + 256] = 0.f;
    ws[(size_t)b*WS_STRIDE + 257] = 0.f;
    ws[(size_t)b*WS_STRIDE + 258] = 0.f;
    ws[(size_t)b*WS_STRIDE + 259] = 0.f;
}

// per-(b,l) gold + length, block-reduced, 4 atomics per batch
__global__ __launch_bounds__(256) void gold_kernel(
    const float* __restrict__ trans, const float* __restrict__ feats,
    const int* __restrict__ mask, const int* __restrict__ tags,
    float* __restrict__ ws)
{
    int idx = blockIdx.x * 256 + threadIdx.x;   // b*L + l (block = 1/4 batch)
    int b = idx >> 10;
    float gv = 0.f, ln = 0.f;
    if (mask[idx] != 0) {
        ln = 1.f;
        int l  = idx & (CRF_L - 1);
        int tg = tags[idx];
        gv = feats[(size_t)idx * CRF_T + tg];
        if (l > 0) gv += trans[tags[idx-1] * CRF_T + tg];
    }
    int lane = threadIdx.x & 63, w = threadIdx.x >> 6;
    for (int o = 32; o > 0; o >>= 1) {
        gv += __shfl_down(gv, o, 64);
        ln += __shfl_down(ln, o, 64);
    }
    __shared__ float sg[4], sl[4];
    if (lane == 0) { sg[w] = gv; sl[w] = ln; }
    __syncthreads();
    if (threadIdx.x == 0) {
        atomicAdd(&ws[(size_t)b*WS_STRIDE + 258], sg[0]+sg[1]+sg[2]+sg[3]);
        atomicAdd(&ws[(size_t)b*WS_STRIDE + 259], sl[0]+sl[1]+sl[2]+sl[3]);
    }
}

// One wave = 16 batches x one direction. x lives in MFMA accumulators:
// lane (g2,c): acc m reg i = x_{batch c}[16m+4g2+i]. Self-feeding k-map
// tau(32kt+8g2+e) = 16(2kt+(e>>2)) + 4g2 + (e&3) makes next step's B-frags
// in-lane register renames of the packed accs. Zero LDS/barriers/shuffles
// on the chain. Layouts HW-verified by rounds 2-10.
template<bool ISF>
static __device__ __forceinline__ void run_dir(
    const float* __restrict__ trans, const float* __restrict__ feats,
    float* __restrict__ ws, int W, int lane)
{
    const int g2 = lane >> 4;
    const int c  = lane & 15;
    const int bc = 16 * W + c;

    const int len = (int)ws[(size_t)bc*WS_STRIDE + 259];
    const int mid = len >> 1;
    const int ns  = ISF ? mid : (len - 1 - mid);
    int mx = ns;
#pragma unroll
    for (int o = 1; o < 16; o <<= 1) {
        int t = __shfl_xor(mx, o, 64); mx = t > mx ? t : mx;
    }

    // ---- A = transition matrix in registers (one-time) ----
    // fwd: A[out=16m+c][in=tau] = E[in][out];  bwd: = E[out][in]
    bf16x8 A[8][4];
#pragma unroll
    for (int m = 0; m < 8; ++m)
#pragma unroll
        for (int kt = 0; kt < 4; ++kt) {
            bf16x8 a;
#pragma unroll
            for (int i = 0; i < 8; ++i) {
                int tau = 16*(2*kt + (i>>2)) + 4*g2 + (i&3);
                int idx = ISF ? (tau*CRF_T + 16*m + c) : ((16*m + c)*CRF_T + tau);
                a[i] = (short)f2bf(__expf(trans[idx]));
            }
            A[m][kt] = a;
        }

    const float* fb = feats + (size_t)bc * CRF_L * CRF_T;

    float x[8][4];
    if (ISF) {
#pragma unroll
        for (int m = 0; m < 8; ++m) {
            f32x4 v = *(const f32x4*)(fb + 16*m + 4*g2);
#pragma unroll
            for (int i = 0; i < 4; ++i) x[m][i] = __expf(v[i]);
        }
    } else {
#pragma unroll
        for (int m = 0; m < 8; ++m)
#pragma unroll
            for (int i = 0; i < 4; ++i) x[m][i] = 1.0f;
    }

    // F row for step s: fwd -> s, bwd -> len - s (clamped)
#define ROWPTR(S_) (fb + (size_t)(ISF ? (S_) : ((len - (S_)) < 0 ? 0 : (len - (S_)))) * CRF_T)

    float Fe[8][4], rawA[8][4], rawB[8][4];
#pragma unroll
    for (int m = 0; m < 8; ++m) {
        f32x4 v1 = *(const f32x4*)(ROWPTR(1) + 16*m + 4*g2);
        f32x4 v2 = *(const f32x4*)(ROWPTR(2) + 16*m + 4*g2);
        f32x4 v3 = *(const f32x4*)(ROWPTR(3) + 16*m + 4*g2);
#pragma unroll
        for (int i = 0; i < 4; ++i) {
            Fe[m][i] = __expf(v1[i]); rawA[m][i] = v2[i]; rawB[m][i] = v3[i];
        }
    }

    float kap = 0.f, sig = 1.f, lnp = 0.f;
    const f32x4 Z = {};

    // IS_ODD step: Fs = Fe, then compute norm (sig/lnp) from updated x.
    // even step: Fs = Fe*sig, kap += lnp (guarded). Freeze via per-lane select.
#define FSTEP(S, BANK, IS_ODD) do {                                            \
    unsigned pk[8][2];                                                         \
    _Pragma("unroll")                                                          \
    for (int m = 0; m < 8; ++m) {                                              \
        if (ISF) {                                                             \
            pk[m][0] = pack2(x[m][0], x[m][1]);                                \
            pk[m][1] = pack2(x[m][2], x[m][3]);                                \
        } else {                                                               \
            float f0 = (IS_ODD) ? Fe[m][0] : Fe[m][0]*sig;                     \
            float f1 = (IS_ODD) ? Fe[m][1] : Fe[m][1]*sig;                     \
            float f2 = (IS_ODD) ? Fe[m][2] : Fe[m][2]*sig;                     \
            float f3 = (IS_ODD) ? Fe[m][3] : Fe[m][3]*sig;                     \
            pk[m][0] = pack2(f0*x[m][0], f1*x[m][1]);                          \
            pk[m][1] = pack2(f2*x[m][2], f3*x[m][3]);                          \
        }                                                                      \
    }                                                                          \
    bf16x8 B0, B1, B2, B3;                                                     \
    { u32x4 q0 = {pk[0][0],pk[0][1],pk[1][0],pk[1][1]};                        \
      u32x4 q1 = {pk[2][0],pk[2][1],pk[3][0],pk[3][1]};                        \
      u32x4 q2 = {pk[4][0],pk[4][1],pk[5][0],pk[5][1]};                        \
      u32x4 q3 = {pk[6][0],pk[6][1],pk[7][0],pk[7][1]};                        \
      B0 = __builtin_bit_cast(bf16x8, q0); B1 = __builtin_bit_cast(bf16x8, q1);\
      B2 = __builtin_bit_cast(bf16x8, q2); B3 = __builtin_bit_cast(bf16x8, q3);}\
    f32x4 acc[8];                                                              \
    _Pragma("unroll") for (int m = 0; m < 8; ++m) acc[m] = MF(A[m][0], B0, Z); \
    _Pragma("unroll") for (int m = 0; m < 8; ++m) acc[m] = MF(A[m][1], B1, acc[m]); \
    _Pragma("unroll") for (int m = 0; m < 8; ++m) acc[m] = MF(A[m][2], B2, acc[m]); \
    _Pragma("unroll") for (int m = 0; m < 8; ++m) acc[m] = MF(A[m][3], B3, acc[m]); \
    const bool act_ = (S) <= ns;                                               \
    if (!(IS_ODD)) kap += act_ ? lnp : 0.0f;                                   \
    _Pragma("unroll")                                                          \
    for (int m = 0; m < 8; ++m)                                                \
        _Pragma("unroll")                                                      \
        for (int i = 0; i < 4; ++i) {                                          \
            float xn_;                                                         \
            if (ISF) {                                                         \
                float fs_ = (IS_ODD) ? Fe[m][i] : Fe[m][i]*sig;                \
                xn_ = fs_ * acc[m][i];                                         \
            } else xn_ = acc[m][i];                                            \
            x[m][i] = act_ ? xn_ : x[m][i];                                    \
        }                                                                      \
    if (IS_ODD) {                                                              \
        float nm_ = x[0][0];                                                   \
        _Pragma("unroll")                                                      \
        for (int m = 0; m < 8; ++m)                                            \
            _Pragma("unroll")                                                  \
            for (int i = 0; i < 4; ++i) nm_ = fmaxf(nm_, x[m][i]);             \
        nm_ = fmaxf(nm_, __shfl_xor(nm_, 16, 64));                             \
        nm_ = fmaxf(nm_, __shfl_xor(nm_, 32, 64));                             \
        sig = __builtin_amdgcn_rcpf(nm_);                                      \
        lnp = __logf(nm_);                                                     \
    }                                                                          \
    _Pragma("unroll")                                                          \
    for (int m = 0; m < 8; ++m)                                                \
        _Pragma("unroll")                                                      \
        for (int i = 0; i < 4; ++i) Fe[m][i] = __expf(BANK[m][i]);             \
    { const float* rp_ = ROWPTR((S) + 3);                                      \
      _Pragma("unroll")                                                        \
      for (int m = 0; m < 8; ++m) {                                            \
          f32x4 v_ = *(const f32x4*)(rp_ + 16*m + 4*g2);                       \
          _Pragma("unroll")                                                    \
          for (int i = 0; i < 4; ++i) BANK[m][i] = v_[i];                      \
      } }                                                                      \
} while (0)

    int s = 1;
    for (; s + 1 <= mx; s += 2) {
        FSTEP(s,     rawA, true);
        FSTEP(s + 1, rawB, false);
    }
    if (s <= mx) FSTEP(s, rawA, true);

    // ---- write frozen midpoint state ----
    float* wsb = ws + (size_t)bc*WS_STRIDE + (ISF ? 0 : 128);
#pragma unroll
    for (int m = 0; m < 8; ++m) {
        f32x4 v; v[0]=x[m][0]; v[1]=x[m][1]; v[2]=x[m][2]; v[3]=x[m][3];
        *(f32x4*)(wsb + 16*m + 4*g2) = v;
    }
    if (g2 == 0) ws[(size_t)bc*WS_STRIDE + 256 + (ISF ? 0 : 1)] = kap;
#undef FSTEP
#undef ROWPTR
}

// 32 blocks x 64 threads: block = (16-batch group) x direction
__global__ __launch_bounds__(64, 1) void forward_kernel(
    const float* __restrict__ trans, const float* __restrict__ feats,
    float* __restrict__ ws)
{
    const int lane = threadIdx.x;
    const int W    = blockIdx.x >> 1;
    if (blockIdx.x & 1) run_dir<false>(trans, feats, ws, W, lane);
    else                run_dir<true >(trans, feats, ws, W, lane);
}

// one block, thread t = batch t: loss_b = kf + kb + log(sum xf.xb) - gold
__global__ __launch_bounds__(256) void combine_kernel(
    const float* __restrict__ ws, float* __restrict__ out)
{
    const int t    = threadIdx.x;
    const int lane = t & 63;
    const int w    = t >> 6;
    const float4* pf = (const float4*)(ws + (size_t)t * WS_STRIDE);
    const float4* pb = pf + 32;
    float dot = 0.0f;
#pragma unroll
    for (int k = 0; k < 32; ++k) {
        float4 a = pf[k], bb = pb[k];
        dot += a.x * bb.x + a.y * bb.y + a.z * bb.z + a.w * bb.w;
    }
    const float* ps = ws + (size_t)t * WS_STRIDE;
    float val = ps[256] + ps[257] + __logf(dot) - ps[258];
    for (int o = 32; o > 0; o >>= 1) val += __shfl_down(val, o, 64);
    __shared__ float sw[4];
    if (lane == 0) sw[w] = val;
    __syncthreads();
    if (t == 0) out[0] = sw[0] + sw[1] + sw[2] + sw[3];
}

extern "C" void kernel_launch(void* const* d_in, const int* in_sizes, int n_in,
                              void* d_out, int out_size, void* d_ws, size_t ws_size,
                              hipStream_t stream) {
    const float* trans = (const float*)d_in[0];
    const float* feats = (const float*)d_in[1];
    const int*   mask  = (const int*)d_in[2];
    const int*   tags  = (const int*)d_in[3];
    float*       out   = (float*)d_out;
    float*       ws    = (float*)d_ws;

    hipLaunchKernelGGL(zero_ws_kernel, dim3(1), dim3(256), 0, stream, ws);
    hipLaunchKernelGGL(gold_kernel, dim3(CRF_B * CRF_L / 256), dim3(256), 0, stream,
                       trans, feats, mask, tags, ws);
    hipLaunchKernelGGL(forward_kernel, dim3(32), dim3(64), 0, stream,
                       trans, feats, ws);
    hipLaunchKernelGGL(combine_kernel, dim3(1), dim3(256), 0, stream, ws, out);
}

// Round 14
// 328.747 us; speedup vs baseline: 1.8326x; 1.4158x over previous
//
#include <hip/hip_runtime.h>

#define CRF_B 256
#define CRF_L 1024
#define CRF_T 128
#define WS_STRIDE 264   // per batch: xf[128], xb[128], kf, kb, gold, len, pad

typedef __attribute__((ext_vector_type(8))) short bf16x8;
typedef __attribute__((ext_vector_type(4))) float f32x4;
typedef __attribute__((ext_vector_type(2))) short short2v;

#define MF(a,b,c_) __builtin_amdgcn_mfma_f32_16x16x32_bf16((a),(b),(c_),0,0,0)
// intra-wave LDS ordering: write retired before subsequent reads; no barrier
#define LGKM0() asm volatile("s_waitcnt lgkmcnt(0)" ::: "memory")

static __device__ __forceinline__ unsigned short f2bf(float x) {
    union { float f; unsigned u; } v; v.f = x;
    unsigned r = v.u + 0x7FFFu + ((v.u >> 16) & 1u);   // RNE (one-time E build)
    return (unsigned short)(r >> 16);
}
// truncating bf16 pair pack [b:a]
static __device__ __forceinline__ unsigned pack2(float a, float b) {
    return (__builtin_bit_cast(unsigned, b) & 0xFFFF0000u) |
           (__builtin_bit_cast(unsigned, a) >> 16);
}
static __device__ __forceinline__ short2v bmax2(short2v a, short2v b) {
    return __builtin_elementwise_max(a, b);   // bf16>=0: i16 order-preserving
}
static __device__ __forceinline__ short2v fragmax(bf16x8 a) {
    short2v q0 = __builtin_shufflevector(a, a, 0, 1);
    short2v q1 = __builtin_shufflevector(a, a, 2, 3);
    short2v q2 = __builtin_shufflevector(a, a, 4, 5);
    short2v q3 = __builtin_shufflevector(a, a, 6, 7);
    return bmax2(bmax2(q0, q1), bmax2(q2, q3));
}

__global__ __launch_bounds__(256) void zero_ws_kernel(float* __restrict__ ws) {
    int b = threadIdx.x;
    ws[(size_t)b*WS_STRIDE + 256] = 0.f;
    ws[(size_t)b*WS_STRIDE + 257] = 0.f;
    ws[(size_t)b*WS_STRIDE + 258] = 0.f;
    ws[(size_t)b*WS_STRIDE + 259] = 0.f;
}

// per-(b,l) gold + length, block-reduced, 2 atomics per block
__global__ __launch_bounds__(256) void gold_kernel(
    const float* __restrict__ trans, const float* __restrict__ feats,
    const int* __restrict__ mask, const int* __restrict__ tags,
    float* __restrict__ ws)
{
    int idx = blockIdx.x * 256 + threadIdx.x;   // b*L + l
    int b = idx >> 10;
    float gv = 0.f, ln = 0.f;
    if (mask[idx] != 0) {
        ln = 1.f;
        int l  = idx & (CRF_L - 1);
        int tg = tags[idx];
        gv = feats[(size_t)idx * CRF_T + tg];
        if (l > 0) gv += trans[tags[idx-1] * CRF_T + tg];
    }
    int lane = threadIdx.x & 63, w = threadIdx.x >> 6;
    for (int o = 32; o > 0; o >>= 1) {
        gv += __shfl_down(gv, o, 64);
        ln += __shfl_down(ln, o, 64);
    }
    __shared__ float sg[4], sl[4];
    if (lane == 0) { sg[w] = gv; sl[w] = ln; }
    __syncthreads();
    if (threadIdx.x == 0) {
        atomicAdd(&ws[(size_t)b*WS_STRIDE + 258], sg[0]+sg[1]+sg[2]+sg[3]);
        atomicAdd(&ws[(size_t)b*WS_STRIDE + 259], sl[0]+sl[1]+sl[2]+sl[3]);
    }
}

// One WAVE = one direction-chain of one batch. Whole 128-col state lives in
// the wave: lane (g2,c) owns cols cA=16g2+c, cB=cA+64. Publish = one b32 at
// 4*lane; position<->tag bijection tau(kt,g2,e)=16kt+64(e&1)+4g2+(e>>1);
// B built with same tau (operand symmetry -> cancels). No barriers anywhere.
// Norm: r7's fragmax-of-read-frags + 2 shfl, every 2 steps, sig applied to d
// with exact kap pairing.
template<bool ISF>
static __device__ __forceinline__ void run_chain(
    const float* __restrict__ trans, const float* __restrict__ feats,
    float* __restrict__ ws, int b, int lane, char* __restrict__ sx)
{
    const int g2 = lane >> 4, c = lane & 15;
    const int cA = 16*g2 + c, cB = cA + 64;
    const int len = (int)ws[(size_t)b*WS_STRIDE + 259];   // in [512,1024]
    const int mid = len >> 1;
    const int ns  = ISF ? mid : (len - 1 - mid);

    // ---- B fragments (one-time): fwd E[tau][col], bwd E[col][tau] ----
    bf16x8 Bf[8][4];
#pragma unroll
    for (int m = 0; m < 8; ++m)
#pragma unroll
        for (int kt = 0; kt < 4; ++kt) {
            bf16x8 a;
#pragma unroll
            for (int e = 0; e < 8; ++e) {
                int tau = 16*kt + 64*(e&1) + 4*g2 + (e>>1);
                int col = 16*m + c;
                int idx = ISF ? (tau*CRF_T + col) : (col*CRF_T + tau);
                a[e] = (short)f2bf(__expf(trans[idx]));
            }
            Bf[m][kt] = a;
        }

    const float* fb = feats + (size_t)b * CRF_L * CRF_T;
    // row for step S: fwd -> S, bwd -> len - S
#define RP(S_) (fb + (size_t)(ISF ? (S_) : (len - (S_))) * CRF_T)

    float xA, xB;
    if (ISF) { xA = __expf(fb[cA]); xB = __expf(fb[cB]); }
    else     { xA = 1.0f;           xB = 1.0f;           }
    float FcA = __expf(RP(1)[cA]), FcB = __expf(RP(1)[cB]);
    float pA0 = RP(2)[cA], pA1 = RP(2)[cB];
    float pB0 = RP(3)[cA], pB1 = RP(3)[cB];
    float pC0 = RP(4)[cA], pC1 = RP(4)[cB];
    float pD0 = RP(5)[cA], pD1 = RP(5)[cB];

    float kap = 0.0f;
    const f32x4 Z = {};

#define CSTEP(S_, PA_, PB_, NORM_) do {                                        \
    unsigned pk_ = ISF ? pack2(xA, xB) : pack2(FcA*xA, FcB*xB);                \
    *(unsigned*)(sx + 4*lane) = pk_;                                           \
    LGKM0();                                                                   \
    bf16x8 A0_ = *(const bf16x8*)(sx +   0 + 16*g2);                           \
    bf16x8 A1_ = *(const bf16x8*)(sx +  64 + 16*g2);                           \
    bf16x8 A2_ = *(const bf16x8*)(sx + 128 + 16*g2);                           \
    bf16x8 A3_ = *(const bf16x8*)(sx + 192 + 16*g2);                           \
    f32x4 a0_ = MF(A0_, Bf[0][0], Z);  f32x4 a1_ = MF(A0_, Bf[1][0], Z);       \
    f32x4 a2_ = MF(A0_, Bf[2][0], Z);  f32x4 a3_ = MF(A0_, Bf[3][0], Z);       \
    f32x4 a4_ = MF(A0_, Bf[4][0], Z);  f32x4 a5_ = MF(A0_, Bf[5][0], Z);       \
    f32x4 a6_ = MF(A0_, Bf[6][0], Z);  f32x4 a7_ = MF(A0_, Bf[7][0], Z);       \
    a0_ = MF(A1_, Bf[0][1], a0_);  a1_ = MF(A1_, Bf[1][1], a1_);               \
    a2_ = MF(A1_, Bf[2][1], a2_);  a3_ = MF(A1_, Bf[3][1], a3_);               \
    a4_ = MF(A1_, Bf[4][1], a4_);  a5_ = MF(A1_, Bf[5][1], a5_);               \
    a6_ = MF(A1_, Bf[6][1], a6_);  a7_ = MF(A1_, Bf[7][1], a7_);               \
    a0_ = MF(A2_, Bf[0][2], a0_);  a1_ = MF(A2_, Bf[1][2], a1_);               \
    a2_ = MF(A2_, Bf[2][2], a2_);  a3_ = MF(A2_, Bf[3][2], a3_);               \
    a4_ = MF(A2_, Bf[4][2], a4_);  a5_ = MF(A2_, Bf[5][2], a5_);               \
    a6_ = MF(A2_, Bf[6][2], a6_);  a7_ = MF(A2_, Bf[7][2], a7_);               \
    a0_ = MF(A3_, Bf[0][3], a0_);  a1_ = MF(A3_, Bf[1][3], a1_);               \
    a2_ = MF(A3_, Bf[2][3], a2_);  a3_ = MF(A3_, Bf[3][3], a3_);               \
    a4_ = MF(A3_, Bf[4][3], a4_);  a5_ = MF(A3_, Bf[5][3], a5_);               \
    a6_ = MF(A3_, Bf[6][3], a6_);  a7_ = MF(A3_, Bf[7][3], a7_);               \
    float dA_ = (g2 < 2) ? (g2 == 0 ? a0_[0] : a1_[0])                         \
                         : (g2 == 2 ? a2_[0] : a3_[0]);                        \
    float dB_ = (g2 < 2) ? (g2 == 0 ? a4_[0] : a5_[0])                         \
                         : (g2 == 2 ? a6_[0] : a7_[0]);                        \
    if (NORM_) {                                                               \
        short2v mx_ = bmax2(bmax2(fragmax(A0_), fragmax(A1_)),                 \
                            bmax2(fragmax(A2_), fragmax(A3_)));                \
        unsigned mu_ = __builtin_bit_cast(unsigned, mx_);                      \
        float nm_ = fmaxf(__builtin_bit_cast(float, mu_ << 16),                \
                          __builtin_bit_cast(float, mu_ & 0xFFFF0000u));       \
        nm_ = fmaxf(nm_, __shfl_xor(nm_, 16, 64));                             \
        nm_ = fmaxf(nm_, __shfl_xor(nm_, 32, 64));                             \
        float sg_ = __builtin_amdgcn_rcpf(nm_);                                \
        kap += __logf(nm_);                                                    \
        dA_ *= sg_; dB_ *= sg_;                                                \
    }                                                                          \
    if (ISF) { xA = FcA * dA_; xB = FcB * dB_; }                               \
    else     { xA = dA_;       xB = dB_;       }                               \
    FcA = __expf(PA_);  FcB = __expf(PB_);                                     \
    { const float* rp_ = RP((S_) + 5);                                         \
      PA_ = rp_[cA];  PB_ = rp_[cB]; }                                         \
} while (0)

    int s = 1;
    for (; s + 3 <= ns; s += 4) {
        CSTEP(s,     pA0, pA1, true);
        CSTEP(s + 1, pB0, pB1, false);
        CSTEP(s + 2, pC0, pC1, true);
        CSTEP(s + 3, pD0, pD1, false);
    }
    if (s <= ns) { CSTEP(s, pA0, pA1, true);  s++; }
    if (s <= ns) { CSTEP(s, pB0, pB1, false); s++; }
    if (s <= ns) { CSTEP(s, pC0, pC1, true); }

    // ---- write midpoint state ----
    float* wsb = ws + (size_t)b * WS_STRIDE + (ISF ? 0 : 128);
    wsb[cA] = xA;
    wsb[cB] = xB;
    if (lane == 0) ws[(size_t)b*WS_STRIDE + 256 + (ISF ? 0 : 1)] = kap;
#undef CSTEP
#undef RP
}

// 64 blocks x 512 threads = 512 waves: wave = (batch, dir). Waves never sync.
__global__ __launch_bounds__(512, 2) void forward_kernel(
    const float* __restrict__ trans, const float* __restrict__ feats,
    float* __restrict__ ws)
{
    __shared__ __align__(16) char s_x[8][256];
    const int t    = threadIdx.x;
    const int widx = t >> 6;
    const int lane = t & 63;
    const int gw   = blockIdx.x * 8 + widx;
    const int b    = gw >> 1;
    if (gw & 1) run_chain<false>(trans, feats, ws, b, lane, s_x[widx]);
    else        run_chain<true >(trans, feats, ws, b, lane, s_x[widx]);
}

// one block, thread t = batch t: loss_b = kf + kb + log(sum xf.xb) - gold
__global__ __launch_bounds__(256) void combine_kernel(
    const float* __restrict__ ws, float* __restrict__ out)
{
    const int t    = threadIdx.x;
    const int lane = t & 63;
    const int w    = t >> 6;
    const float4* pf = (const float4*)(ws + (size_t)t * WS_STRIDE);
    const float4* pb = pf + 32;
    float dot = 0.0f;
#pragma unroll
    for (int k = 0; k < 32; ++k) {
        float4 a = pf[k], bb = pb[k];
        dot += a.x * bb.x + a.y * bb.y + a.z * bb.z + a.w * bb.w;
    }
    const float* ps = ws + (size_t)t * WS_STRIDE;
    float val = ps[256] + ps[257] + __logf(dot) - ps[258];
    for (int o = 32; o > 0; o >>= 1) val += __shfl_down(val, o, 64);
    __shared__ float sw[4];
    if (lane == 0) sw[w] = val;
    __syncthreads();
    if (t == 0) out[0] = sw[0] + sw[1] + sw[2] + sw[3];
}

extern "C" void kernel_launch(void* const* d_in, const int* in_sizes, int n_in,
                              void* d_out, int out_size, void* d_ws, size_t ws_size,
                              hipStream_t stream) {
    const float* trans = (const float*)d_in[0];
    const float* feats = (const float*)d_in[1];
    const int*   mask  = (const int*)d_in[2];
    const int*   tags  = (const int*)d_in[3];
    float*       out   = (float*)d_out;
    float*       ws    = (float*)d_ws;

    hipLaunchKernelGGL(zero_ws_kernel, dim3(1), dim3(256), 0, stream, ws);
    hipLaunchKernelGGL(gold_kernel, dim3(CRF_B * CRF_L / 256), dim3(256), 0, stream,
                       trans, feats, mask, tags, ws);
    hipLaunchKernelGGL(forward_kernel, dim3(64), dim3(512), 0, stream,
                       trans, feats, ws);
    hipLaunchKernelGGL(combine_kernel, dim3(1), dim3(256), 0, stream, ws, out);
}

// Round 15
// 255.679 us; speedup vs baseline: 2.3564x; 1.2858x over previous
//
#include <hip/hip_runtime.h>

#define CRF_B 256
#define CRF_L 1024
#define CRF_T 128
#define WS_STRIDE 264   // per batch: xf[128], xb[128], kf, kb, gold, len, pad

typedef __attribute__((ext_vector_type(8))) short bf16x8;
typedef __attribute__((ext_vector_type(4))) float f32x4;
typedef __attribute__((ext_vector_type(2))) short short2v;

#define MF(a,b,c_) __builtin_amdgcn_mfma_f32_16x16x32_bf16((a),(b),(c_),0,0,0)

static __device__ __forceinline__ unsigned short f2bf(float x) {
    union { float f; unsigned u; } v; v.f = x;
    unsigned r = v.u + 0x7FFFu + ((v.u >> 16) & 1u);   // RNE (one-time E build)
    return (unsigned short)(r >> 16);
}
// truncating bf16 pair pack [b:a]
static __device__ __forceinline__ unsigned pack2(float a, float b) {
    return (__builtin_bit_cast(unsigned, b) & 0xFFFF0000u) |
           (__builtin_bit_cast(unsigned, a) >> 16);
}
static __device__ __forceinline__ short2v bmax2(short2v a, short2v b) {
    return __builtin_elementwise_max(a, b);   // bf16>=0: i16 order-preserving
}
static __device__ __forceinline__ short2v fragmax(bf16x8 a) {
    short2v q0 = __builtin_shufflevector(a, a, 0, 1);
    short2v q1 = __builtin_shufflevector(a, a, 2, 3);
    short2v q2 = __builtin_shufflevector(a, a, 4, 5);
    short2v q3 = __builtin_shufflevector(a, a, 6, 7);
    return bmax2(bmax2(q0, q1), bmax2(q2, q3));
}

__global__ __launch_bounds__(256) void zero_ws_kernel(float* __restrict__ ws) {
    int b = threadIdx.x;
    ws[(size_t)b*WS_STRIDE + 256] = 0.f;
    ws[(size_t)b*WS_STRIDE + 257] = 0.f;
    ws[(size_t)b*WS_STRIDE + 258] = 0.f;
    ws[(size_t)b*WS_STRIDE + 259] = 0.f;
}

// per-(b,l) gold + length, block-reduced, 2 atomics per block
__global__ __launch_bounds__(256) void gold_kernel(
    const float* __restrict__ trans, const float* __restrict__ feats,
    const int* __restrict__ mask, const int* __restrict__ tags,
    float* __restrict__ ws)
{
    int idx = blockIdx.x * 256 + threadIdx.x;   // b*L + l
    int b = idx >> 10;
    float gv = 0.f, ln = 0.f;
    if (mask[idx] != 0) {
        ln = 1.f;
        int l  = idx & (CRF_L - 1);
        int tg = tags[idx];
        gv = feats[(size_t)idx * CRF_T + tg];
        if (l > 0) gv += trans[tags[idx-1] * CRF_T + tg];
    }
    int lane = threadIdx.x & 63, w = threadIdx.x >> 6;
    for (int o = 32; o > 0; o >>= 1) {
        gv += __shfl_down(gv, o, 64);
        ln += __shfl_down(ln, o, 64);
    }
    __shared__ float sg[4], sl[4];
    if (lane == 0) { sg[w] = gv; sl[w] = ln; }
    __syncthreads();
    if (threadIdx.x == 0) {
        atomicAdd(&ws[(size_t)b*WS_STRIDE + 258], sg[0]+sg[1]+sg[2]+sg[3]);
        atomicAdd(&ws[(size_t)b*WS_STRIDE + 259], sl[0]+sl[1]+sl[2]+sl[3]);
    }
}

// One WAVE = one direction-chain of one batch. Lane (g2,c) owns cols
// cA=16g2+c, cB=cA+64; publish = one b32 at 4*lane; re-read as 4 b128
// A-fragments (same-wave DS ops are in-order: NO fence, NO barrier).
// tau(kt,g2,e)=16kt+64(e&1)+4g2+(e>>1); B built with same tau (operand
// symmetry -> cancels). Norm: fragmax of read frags + 2 shfl, every 2 steps.
template<bool ISF>
static __device__ __forceinline__ void run_chain(
    const float* __restrict__ trans, const float* __restrict__ feats,
    float* __restrict__ ws, int b, int lane, char* __restrict__ sx)
{
    const int g2 = lane >> 4, c = lane & 15;
    const int cA = 16*g2 + c, cB = cA + 64;
    const int len = (int)ws[(size_t)b*WS_STRIDE + 259];   // in [512,1024]
    const int mid = len >> 1;
    const int ns  = ISF ? mid : (len - 1 - mid);

    // ---- B fragments (one-time): fwd E[tau][col], bwd E[col][tau] ----
    bf16x8 Bf[8][4];
#pragma unroll
    for (int m = 0; m < 8; ++m)
#pragma unroll
        for (int kt = 0; kt < 4; ++kt) {
            bf16x8 a;
#pragma unroll
            for (int e = 0; e < 8; ++e) {
                int tau = 16*kt + 64*(e&1) + 4*g2 + (e>>1);
                int col = 16*m + c;
                int idx = ISF ? (tau*CRF_T + col) : (col*CRF_T + tau);
                a[e] = (short)f2bf(__expf(trans[idx]));
            }
            Bf[m][kt] = a;
        }

    const float* fb = feats + (size_t)b * CRF_L * CRF_T;
    // row for step S: fwd -> S, bwd -> len - S
#define RP(S_) (fb + (size_t)(ISF ? (S_) : (len - (S_))) * CRF_T)

    float xA, xB;
    if (ISF) { xA = __expf(fb[cA]); xB = __expf(fb[cB]); }
    else     { xA = 1.0f;           xB = 1.0f;           }
    float FcA = __expf(RP(1)[cA]), FcB = __expf(RP(1)[cB]);
    float pA0 = RP(2)[cA], pA1 = RP(2)[cB];
    float pB0 = RP(3)[cA], pB1 = RP(3)[cB];
    float pC0 = RP(4)[cA], pC1 = RP(4)[cB];
    float pD0 = RP(5)[cA], pD1 = RP(5)[cB];

    float kap = 0.0f;
    const f32x4 Z = {};

#define CSTEP(S_, PA_, PB_, NORM_) do {                                        \
    unsigned pk_ = ISF ? pack2(xA, xB) : pack2(FcA*xA, FcB*xB);                \
    *(unsigned*)(sx + 4*lane) = pk_;                                           \
    bf16x8 A0_ = *(const bf16x8*)(sx +   0 + 16*g2);                           \
    bf16x8 A1_ = *(const bf16x8*)(sx +  64 + 16*g2);                           \
    bf16x8 A2_ = *(const bf16x8*)(sx + 128 + 16*g2);                           \
    bf16x8 A3_ = *(const bf16x8*)(sx + 192 + 16*g2);                           \
    f32x4 u0_ = MF(A0_, Bf[0][0], Z);  f32x4 u1_ = MF(A0_, Bf[1][0], Z);       \
    f32x4 u2_ = MF(A0_, Bf[2][0], Z);  f32x4 u3_ = MF(A0_, Bf[3][0], Z);       \
    f32x4 u4_ = MF(A0_, Bf[4][0], Z);  f32x4 u5_ = MF(A0_, Bf[5][0], Z);       \
    f32x4 u6_ = MF(A0_, Bf[6][0], Z);  f32x4 u7_ = MF(A0_, Bf[7][0], Z);       \
    f32x4 v0_ = MF(A1_, Bf[0][1], Z);  f32x4 v1_ = MF(A1_, Bf[1][1], Z);       \
    f32x4 v2_ = MF(A1_, Bf[2][1], Z);  f32x4 v3_ = MF(A1_, Bf[3][1], Z);       \
    f32x4 v4_ = MF(A1_, Bf[4][1], Z);  f32x4 v5_ = MF(A1_, Bf[5][1], Z);       \
    f32x4 v6_ = MF(A1_, Bf[6][1], Z);  f32x4 v7_ = MF(A1_, Bf[7][1], Z);       \
    u0_ = MF(A2_, Bf[0][2], u0_);  u1_ = MF(A2_, Bf[1][2], u1_);               \
    u2_ = MF(A2_, Bf[2][2], u2_);  u3_ = MF(A2_, Bf[3][2], u3_);               \
    u4_ = MF(A2_, Bf[4][2], u4_);  u5_ = MF(A2_, Bf[5][2], u5_);               \
    u6_ = MF(A2_, Bf[6][2], u6_);  u7_ = MF(A2_, Bf[7][2], u7_);               \
    v0_ = MF(A3_, Bf[0][3], v0_);  v1_ = MF(A3_, Bf[1][3], v1_);               \
    v2_ = MF(A3_, Bf[2][3], v2_);  v3_ = MF(A3_, Bf[3][3], v3_);               \
    v4_ = MF(A3_, Bf[4][3], v4_);  v5_ = MF(A3_, Bf[5][3], v5_);               \
    v6_ = MF(A3_, Bf[6][3], v6_);  v7_ = MF(A3_, Bf[7][3], v7_);               \
    float d0_ = u0_[0] + v0_[0], d1_ = u1_[0] + v1_[0];                        \
    float d2_ = u2_[0] + v2_[0], d3_ = u3_[0] + v3_[0];                        \
    float d4_ = u4_[0] + v4_[0], d5_ = u5_[0] + v5_[0];                        \
    float d6_ = u6_[0] + v6_[0], d7_ = u7_[0] + v7_[0];                        \
    float dA_ = (g2 < 2) ? (g2 == 0 ? d0_ : d1_) : (g2 == 2 ? d2_ : d3_);      \
    float dB_ = (g2 < 2) ? (g2 == 0 ? d4_ : d5_) : (g2 == 2 ? d6_ : d7_);      \
    if (NORM_) {                                                               \
        short2v mx_ = bmax2(bmax2(fragmax(A0_), fragmax(A1_)),                 \
                            bmax2(fragmax(A2_), fragmax(A3_)));                \
        unsigned mu_ = __builtin_bit_cast(unsigned, mx_);                      \
        float nm_ = fmaxf(__builtin_bit_cast(float, mu_ << 16),                \
                          __builtin_bit_cast(float, mu_ & 0xFFFF0000u));       \
        nm_ = fmaxf(nm_, __shfl_xor(nm_, 16, 64));                             \
        nm_ = fmaxf(nm_, __shfl_xor(nm_, 32, 64));                             \
        float sg_ = __builtin_amdgcn_rcpf(nm_);                                \
        kap += __logf(nm_);                                                    \
        dA_ *= sg_; dB_ *= sg_;                                                \
    }                                                                          \
    if (ISF) { xA = FcA * dA_; xB = FcB * dB_; }                               \
    else     { xA = dA_;       xB = dB_;       }                               \
    FcA = __expf(PA_);  FcB = __expf(PB_);                                     \
    { const float* rp_ = RP((S_) + 5);                                         \
      PA_ = rp_[cA];  PB_ = rp_[cB]; }                                         \
} while (0)

    int s = 1;
    for (; s + 3 <= ns; s += 4) {
        CSTEP(s,     pA0, pA1, true);
        CSTEP(s + 1, pB0, pB1, false);
        CSTEP(s + 2, pC0, pC1, true);
        CSTEP(s + 3, pD0, pD1, false);
    }
    if (s <= ns) { CSTEP(s, pA0, pA1, true);  s++; }
    if (s <= ns) { CSTEP(s, pB0, pB1, false); s++; }
    if (s <= ns) { CSTEP(s, pC0, pC1, true); }

    // ---- write midpoint state ----
    float* wsb = ws + (size_t)b * WS_STRIDE + (ISF ? 0 : 128);
    wsb[cA] = xA;
    wsb[cB] = xB;
    if (lane == 0) ws[(size_t)b*WS_STRIDE + 256 + (ISF ? 0 : 1)] = kap;
#undef CSTEP
#undef RP
}

// 128 blocks x 256 threads = 512 waves, 1 wave/SIMD on 128 CUs.
// wave = (batch, dir); waves never sync.
__global__ __launch_bounds__(256, 1) void forward_kernel(
    const float* __restrict__ trans, const float* __restrict__ feats,
    float* __restrict__ ws)
{
    __shared__ __align__(16) char s_x[4][256];
    const int t    = threadIdx.x;
    const int widx = t >> 6;
    const int lane = t & 63;
    const int gw   = blockIdx.x * 4 + widx;
    const int b    = gw >> 1;
    if (gw & 1) run_chain<false>(trans, feats, ws, b, lane, s_x[widx]);
    else        run_chain<true >(trans, feats, ws, b, lane, s_x[widx]);
}

// one block, thread t = batch t: loss_b = kf + kb + log(sum xf.xb) - gold
__global__ __launch_bounds__(256) void combine_kernel(
    const float* __restrict__ ws, float* __restrict__ out)
{
    const int t    = threadIdx.x;
    const int lane = t & 63;
    const int w    = t >> 6;
    const float4* pf = (const float4*)(ws + (size_t)t * WS_STRIDE);
    const float4* pb = pf + 32;
    float dot = 0.0f;
#pragma unroll
    for (int k = 0; k < 32; ++k) {
        float4 a = pf[k], bb = pb[k];
        dot += a.x * bb.x + a.y * bb.y + a.z * bb.z + a.w * bb.w;
    }
    const float* ps = ws + (size_t)t * WS_STRIDE;
    float val = ps[256] + ps[257] + __logf(dot) - ps[258];
    for (int o = 32; o > 0; o >>= 1) val += __shfl_down(val, o, 64);
    __shared__ float sw[4];
    if (lane == 0) sw[w] = val;
    __syncthreads();
    if (t == 0) out[0] = sw[0] + sw[1] + sw[2] + sw[3];
}

extern "C" void kernel_launch(void* const* d_in, const int* in_sizes, int n_in,
                              void* d_out, int out_size, void* d_ws, size_t ws_size,
                              hipStream_t stream) {
    const float* trans = (const float*)d_in[0];
    const float* feats = (const float*)d_in[1];
    const int*   mask  = (const int*)d_in[2];
    const int*   tags  = (const int*)d_in[3];
    float*       out   = (float*)d_out;
    float*       ws    = (float*)d_ws;

    hipLaunchKernelGGL(zero_ws_kernel, dim3(1), dim3(256), 0, stream, ws);
    hipLaunchKernelGGL(gold_kernel, dim3(CRF_B * CRF_L / 256), dim3(256), 0, stream,
                       trans, feats, mask, tags, ws);
    hipLaunchKernelGGL(forward_kernel, dim3(128), dim3(256), 0, stream,
                       trans, feats, ws);
    hipLaunchKernelGGL(combine_kernel, dim3(1), dim3(256), 0, stream, ws, out);
}